// Round 2
// baseline (393.747 us; speedup 1.0000x reference)
//
#include <hip/hip_runtime.h>

// ---------------------------------------------------------------------------
// EnsembleTransitionMLP: fused 4-layer MLP over 50 ensembles, bf16 MFMA.
// Round 7 (occupancy + L2 locality):
//  - __launch_bounds__(256,5): 5 blocks/CU (5 x 32KB = 160KB LDS exactly).
//    R6 measured Occupancy 42% / MfmaUtil 41% with 4 blocks/CU; VGPR=64
//    leaves room for 5 waves/SIMD (cap ~102). Falls back to 4 if LDS
//    reservation exists -> risk-free.
//  - XCD-aware block swizzle: lid=(e*128+bb); swz=(lid%8)*800+lid/8 gives
//    each XCD a contiguous ~6.25-ensemble range => weight panels (2.2MB)
//    are L2-resident per XCD. R6 FETCH=66MB vs 16MB packed weights = 4x
//    amplification from round-robin dispatch; this kills it and turns
//    ~900cyc HBM weight loads into ~200cyc L2 hits.
//  - NO a-frag prefetch ring: would push VGPR past 102 and cap us back to
//    4 waves/SIMD. Occupancy does the latency hiding instead.
// Fragment layouts (16x16x32 bf16, same as R2-R6):
//   A: lane l holds A[m=l&15][k=(l>>4)*8+j]   (weights as W^T)
//   B: lane l holds B[k=(l>>4)*8+j][n=l&15]   (h^T: k=feat, n=batch)
//   C/D: lane l, reg r: feat=(l>>4)*4+r, batch=l&15
// ---------------------------------------------------------------------------

typedef __attribute__((ext_vector_type(8))) short short8;
typedef __attribute__((ext_vector_type(4))) float floatx4;

#define NE 50
#define NB 8192
#define OUT_NS_ELEMS (NB * NE * 32)
#define OSTRIDE 48  // shorts; 96B = 16B-aligned rows for b128 reads

__device__ __forceinline__ unsigned short f2bf_rne(float x) {
  unsigned u = __float_as_uint(x);
  u += 0x7fffu + ((u >> 16) & 1u);
  return (unsigned short)(u >> 16);
}
__device__ __forceinline__ float bf2f(unsigned short b) {
  return __uint_as_float(((unsigned)b) << 16);
}
__device__ __forceinline__ floatx4 mfma16(short8 a, short8 b, floatx4 c) {
  return __builtin_amdgcn_mfma_f32_16x16x32_bf16(a, b, c, 0, 0, 0);
}
// pack two f32 -> one dword of bf16 pair, round-half-up
__device__ __forceinline__ unsigned pack_bf2(float lo, float hi) {
  unsigned u0 = __float_as_uint(lo) + 0x8000u;
  unsigned u1 = __float_as_uint(hi) + 0x8000u;
  return __builtin_amdgcn_perm(u1, u0, 0x07060302u);  // [u0.hi16, u1.hi16]
}

__device__ __forceinline__ unsigned short load_bf(const void* p, long i, bool isbf) {
  if (isbf) return ((const unsigned short*)p)[i];
  return f2bf_rne(((const float*)p)[i]);
}
__device__ __forceinline__ float load_f(const void* p, long i, bool isbf) {
  if (isbf) return bf2f(((const unsigned short*)p)[i]);
  return ((const float*)p)[i];
}

// ---------------- mega pack (R3 layout; detection folded in) ----------------
// W pack layout per ensemble (B-fragment order):
//   elt = (((kt*NT + nt)*4 + kb)*16 + ni)*8 + j ; k = kt*32+kb*8+j ; n = nt*16+ni
__device__ void pack_w_panel(const void* __restrict__ src, unsigned short* __restrict__ dst,
                             bool isbf, int e, int kt, int K, int N, int NT, int perE,
                             unsigned short* lds) {
  const int t = threadIdx.x;
  const int Npad = NT * 16;
  const int NP = Npad + 10;
  for (int idx = t; idx < 32 * Npad; idx += 256) {
    int r = idx / Npad, c = idx - r * Npad;
    int k = kt * 32 + r;
    unsigned short v = 0;
    if (k < K && c < N) v = load_bf(src, (long)(e * K + k) * N + c, isbf);
    lds[r * NP + c] = v;
  }
  __syncthreads();
  for (int u = t; u < NT * 64; u += 256) {
    int nt = u >> 6, kb = (u >> 4) & 3, ni = u & 15;
    int n = nt * 16 + ni;
    unsigned v[4];
#pragma unroll
    for (int p = 0; p < 4; ++p) {
      unsigned lo = lds[(kb * 8 + 2 * p) * NP + n];
      unsigned hi = lds[(kb * 8 + 2 * p + 1) * NP + n];
      v[p] = lo | (hi << 16);
    }
    long off = (long)e * perE + ((long)((kt * NT + nt) * 64 + kb * 16 + ni)) * 8;
    *(uint4*)(dst + off) = make_uint4(v[0], v[1], v[2], v[3]);
  }
}

__global__ void k_pack(const void* __restrict__ state, const void* __restrict__ action,
                       const void* __restrict__ W1, const void* __restrict__ W2,
                       const void* __restrict__ W3, const void* __restrict__ W4,
                       const void* __restrict__ b1, const void* __restrict__ b2,
                       const void* __restrict__ b3, const void* __restrict__ b4,
                       int* __restrict__ flag,
                       unsigned short* __restrict__ saP, unsigned short* __restrict__ w1P,
                       unsigned short* __restrict__ w2P, unsigned short* __restrict__ w3P,
                       unsigned short* __restrict__ w4P, float* __restrict__ biasP) {
  __shared__ unsigned short lds[32 * 266];  // 17,024 B
  __shared__ int s_bad;
  const int t = threadIdx.x;
  // --- inline dtype detection: 64 strided samples of W2 raw words ---
  if (t == 0) s_bad = 0;
  __syncthreads();
  if (t < 64) {
    unsigned word = ((const unsigned*)W2)[(long)(t * 32) * 797];
    unsigned short lo = (unsigned short)(word & 0xFFFFu);
    float f = bf2f(lo);
    if (!(fabsf(f) < 16.0f) || lo == 0) s_bad = 1;
  }
  __syncthreads();
  const bool isbf = (s_bad == 0);
  if (blockIdx.x == 0 && t == 0) *flag = isbf ? 1 : 0;

  const int b = blockIdx.x;
  if (b < 400) {
    pack_w_panel(W2, w2P, isbf, b >> 3, b & 7, 256, 256, 16, 65536, lds);
  } else if (b < 800) {
    int bb = b - 400;
    pack_w_panel(W3, w3P, isbf, bb >> 3, bb & 7, 256, 256, 16, 65536, lds);
  } else if (b < 900) {
    int bb = b - 800;
    pack_w_panel(W1, w1P, isbf, bb >> 1, bb & 1, 40, 256, 16, 16384, lds);
  } else if (b < 1300) {
    int bb = b - 900;
    pack_w_panel(W4, w4P, isbf, bb >> 3, bb & 7, 256, 33, 3, 12288, lds);
  } else if (b < 1556) {
    // sa pack (B-frag units): addr(batch=mt*16+mi, k=kb*8+j) =
    //   (mt*128 + kb*16 + mi)*8 + j   (K padded 40->64)
    int u = (b - 1300) * 256 + threadIdx.x;  // < 65536
    int mi = u & 15, kb = (u >> 4) & 7, mt = u >> 7;
    int row = mt * 16 + mi;
    unsigned v[4] = {0u, 0u, 0u, 0u};
    if (kb < 4) {
#pragma unroll
      for (int p = 0; p < 4; ++p) {
        unsigned lo = load_bf(state, (long)row * 32 + kb * 8 + 2 * p, isbf);
        unsigned hi = load_bf(state, (long)row * 32 + kb * 8 + 2 * p + 1, isbf);
        v[p] = lo | (hi << 16);
      }
    } else if (kb == 4) {
#pragma unroll
      for (int p = 0; p < 4; ++p) {
        unsigned lo = load_bf(action, (long)row * 8 + 2 * p, isbf);
        unsigned hi = load_bf(action, (long)row * 8 + 2 * p + 1, isbf);
        v[p] = lo | (hi << 16);
      }
    }
    *(uint4*)(saP + (long)u * 8) = make_uint4(v[0], v[1], v[2], v[3]);
  } else {
    // bias: per e: [b1(256)][b2(256)][b3(256)][b4(48 zero-padded)]
    int gid = (b - 1556) * 256 + threadIdx.x;
    if (gid < NE * 816) {
      int e = gid / 816, r = gid - e * 816;
      float v = 0.0f;
      if (r < 256)      v = load_f(b1, e * 256 + r,         isbf);
      else if (r < 512) v = load_f(b2, e * 256 + (r - 256), isbf);
      else if (r < 768) v = load_f(b3, e * 256 + (r - 512), isbf);
      else { int q = r - 768; if (q < 33) v = load_f(b4, e * 33 + q, isbf); }
      biasP[gid] = v;
    }
  }
}

// ---------------- fused MLP ----------------
// hT in LDS (32KB), B-frag units for BM=64:
//   short addr(k,b) = ((k>>5)*4 + (b>>4))*512 + ((k>>3)&3)*128 + (b&15)*8 + (k&7)
// B-frag read (kt, bt): 16B at ((kt*4 + bt)*64 + l)*8.

__device__ __forceinline__ void store_tile16(const floatx4& a4, unsigned short* hT,
                                             int FT, int BT, int li, int g) {
  int k0 = FT * 16 + g * 4;
  unsigned d0 = pack_bf2(fmaxf(a4[0], 0.0f), fmaxf(a4[1], 0.0f));
  unsigned d1 = pack_bf2(fmaxf(a4[2], 0.0f), fmaxf(a4[3], 0.0f));
  int addr = ((k0 >> 5) * 4 + BT) * 512 + ((k0 >> 3) & 3) * 128 + li * 8 + (k0 & 7);
  *(unsigned long long*)(hT + addr) =
      (unsigned long long)d0 | ((unsigned long long)d1 << 32);
}

// wave wf owns feats [wf*64, wf*64+64) x all 64 batch: acc[4 ftiles][4 btiles]
__device__ __forceinline__ void hidden_layer(const unsigned short* __restrict__ wp,
                                             const float* __restrict__ br,
                                             unsigned short* hT,
                                             int wf, int l, int li, int g) {
  floatx4 acc[4][4];
#pragma unroll
  for (int ot = 0; ot < 4; ++ot) {
    const float4 bq = *(const float4*)(br + wf * 64 + ot * 16 + g * 4);
    floatx4 iv = {bq.x, bq.y, bq.z, bq.w};
#pragma unroll
    for (int bt = 0; bt < 4; ++bt) acc[ot][bt] = iv;
  }
#pragma unroll
  for (int kt = 0; kt < 8; ++kt) {
    short8 a[4];
#pragma unroll
    for (int ot = 0; ot < 4; ++ot)
      a[ot] = *(const short8*)(wp + (long)((kt * 16 + wf * 4 + ot) * 64 + l) * 8);
#pragma unroll
    for (int bt = 0; bt < 4; ++bt) {
      short8 b = *(const short8*)(hT + ((kt * 4 + bt) * 64 + l) * 8);
#pragma unroll
      for (int ot = 0; ot < 4; ++ot)
        acc[ot][bt] = mfma16(a[ot], b, acc[ot][bt]);
    }
  }
  __syncthreads();  // all reads of hT done before in-place overwrite
#pragma unroll
  for (int ot = 0; ot < 4; ++ot)
#pragma unroll
    for (int bt = 0; bt < 4; ++bt)
      store_tile16(acc[ot][bt], hT, wf * 4 + ot, bt, li, g);
  __syncthreads();
}

__global__ __launch_bounds__(256, 5) void k_mlp(
    const unsigned short* __restrict__ sa,
    const unsigned short* __restrict__ w1,
    const unsigned short* __restrict__ w2,
    const unsigned short* __restrict__ w3,
    const unsigned short* __restrict__ w4,
    const float* __restrict__ bias,
    const int* __restrict__ flag,
    float* __restrict__ rewardWS,
    void* __restrict__ outp) {
  __shared__ __attribute__((aligned(16))) unsigned short hT[16384];  // 32 KB
  const int tid = threadIdx.x;
  const int wf = tid >> 6, l = tid & 63, li = l & 15, g = l >> 4;

  // XCD-aware swizzle: hw assigns linear id round-robin (xcd = lid % 8).
  // swz = (lid%8)*800 + lid/8 gives each XCD a contiguous block range =>
  // contiguous ~6.25-ensemble window whose packed panels fit its 4MB L2.
  // 6400 % 8 == 0 -> bijective.
  const int lid = blockIdx.y * 128 + blockIdx.x;
  const int swz = (lid & 7) * 800 + (lid >> 3);
  const int e  = swz >> 7;         // ensemble
  const int bb = swz & 127;        // 64-row batch tile (128 tiles)

  const float* brow = bias + e * 816;
  const bool isbf = (*flag != 0);

  // ---- layer 1: W1^T(256x64) * sa^T(64x64) -> h1^T in LDS ----
  {
    floatx4 acc[4][4];
#pragma unroll
    for (int ot = 0; ot < 4; ++ot) {
      const float4 bq = *(const float4*)(brow + wf * 64 + ot * 16 + g * 4);
      floatx4 iv = {bq.x, bq.y, bq.z, bq.w};
#pragma unroll
      for (int bt = 0; bt < 4; ++bt) acc[ot][bt] = iv;
    }
#pragma unroll
    for (int kt = 0; kt < 2; ++kt) {
      short8 a[4];
#pragma unroll
      for (int ot = 0; ot < 4; ++ot)
        a[ot] = *(const short8*)(w1 + (long)e * 16384 +
                                 (long)((kt * 16 + wf * 4 + ot) * 64 + l) * 8);
#pragma unroll
      for (int bt = 0; bt < 4; ++bt) {
        short8 b = *(const short8*)(sa + (long)((bb * 4 + bt) * 128 + kt * 64 + l) * 8);
#pragma unroll
        for (int ot = 0; ot < 4; ++ot)
          acc[ot][bt] = mfma16(a[ot], b, acc[ot][bt]);
      }
    }
#pragma unroll
    for (int ot = 0; ot < 4; ++ot)
#pragma unroll
      for (int bt = 0; bt < 4; ++bt)
        store_tile16(acc[ot][bt], hT, wf * 4 + ot, bt, li, g);
    __syncthreads();
  }

  // ---- layers 2, 3 ----
  hidden_layer(w2 + (long)e * 65536, brow + 256, hT, wf, l, li, g);
  hidden_layer(w3 + (long)e * 65536, brow + 512, hT, wf, l, li, g);

  // ---- layer 4: W4^T(48x256) * h3^T(256x64); wave wf owns btile wf ----
  const float* brow4 = brow + 768;
  floatx4 acc4[3];
#pragma unroll
  for (int ft = 0; ft < 3; ++ft) {
    const float4 bq = *(const float4*)(brow4 + ft * 16 + g * 4);
    floatx4 iv = {bq.x, bq.y, bq.z, bq.w};
    acc4[ft] = iv;
  }
#pragma unroll
  for (int kt = 0; kt < 8; ++kt) {
    short8 a[3];
#pragma unroll
    for (int ft = 0; ft < 3; ++ft)
      a[ft] = *(const short8*)(w4 + (long)e * 12288 + (long)((kt * 3 + ft) * 64 + l) * 8);
    short8 b = *(const short8*)(hT + ((kt * 4 + wf) * 64 + l) * 8);
#pragma unroll
    for (int ft = 0; ft < 3; ++ft)
      acc4[ft] = mfma16(a[ft], b, acc4[ft]);
  }

  // reward (feat 32 = ft2, g==0, reg 0) -> staged coalesced into ws[e][batch]
  if (g == 0) {
    rewardWS[(long)e * NB + bb * 64 + wf * 16 + li] = acc4[2][0];
  }

  __syncthreads();  // all hT reads done; reuse hT as output staging buffer
  // stage out^T tiles -> osta[batch][feat] (bf16, stride OSTRIDE)
#pragma unroll
  for (int ft = 0; ft < 2; ++ft) {
    int batch = wf * 16 + li;
    unsigned d0 = pack_bf2(acc4[ft][0], acc4[ft][1]);
    unsigned d1 = pack_bf2(acc4[ft][2], acc4[ft][3]);
    *(unsigned long long*)(hT + batch * OSTRIDE + ft * 16 + g * 4) =
        (unsigned long long)d0 | ((unsigned long long)d1 << 32);
  }
  __syncthreads();

  // coalesced store: full 64B line per (batch,e)
  if (isbf) {
    unsigned short* o16 = (unsigned short*)outp;
    int batch = tid >> 2;
    int chunk = tid & 3;  // 8 shorts each
    uint4 v = *(const uint4*)(hT + batch * OSTRIDE + chunk * 8);
    *(uint4*)(o16 + ((long)(bb * 64 + batch) * NE + e) * 32 + chunk * 8) = v;
  } else {
    float* o32 = (float*)outp;
#pragma unroll
    for (int p = 0; p < 2; ++p) {
      int idx = p * 256 + tid;
      int batch = idx >> 3;
      int chunk = idx & 7;  // 4 floats each
      const unsigned short* s = hT + batch * OSTRIDE + chunk * 4;
      *(float4*)(o32 + ((long)(bb * 64 + batch) * NE + e) * 32 + chunk * 4) =
          make_float4(bf2f(s[0]), bf2f(s[1]), bf2f(s[2]), bf2f(s[3]));
    }
  }
}

// ---------------- reward transpose epilogue ----------------
__global__ void k_reward(const float* __restrict__ rw, const int* __restrict__ flag,
                         void* __restrict__ outp) {
  int id = blockIdx.x * 256 + threadIdx.x;
  if (id >= NB * NE) return;
  int b = id / NE, e = id - b * NE;
  float v = rw[(long)e * NB + b];
  if (*flag != 0) {
    unsigned u = __float_as_uint(v) + 0x8000u;
    ((unsigned short*)outp)[OUT_NS_ELEMS + id] = (unsigned short)(u >> 16);
  } else {
    ((float*)outp)[OUT_NS_ELEMS + id] = v;
  }
}

// ---------------------------------------------------------------------------
extern "C" void kernel_launch(void* const* d_in, const int* in_sizes, int n_in,
                              void* d_out, int out_size, void* d_ws, size_t ws_size,
                              hipStream_t stream) {
  const void* state  = d_in[0];
  const void* action = d_in[1];
  const void* W1 = d_in[2];
  const void* b1 = d_in[3];
  const void* W2 = d_in[4];
  const void* b2 = d_in[5];
  const void* W3 = d_in[6];
  const void* b3 = d_in[7];
  const void* W4 = d_in[8];
  const void* b4 = d_in[9];
  (void)in_sizes; (void)n_in; (void)out_size; (void)ws_size;

  char* ws = (char*)d_ws;
  int* flag              = (int*)(ws + 0);
  unsigned short* saP    = (unsigned short*)(ws + 256);        // 1,048,576 B
  unsigned short* w1P    = (unsigned short*)(ws + 1048832);    // 1,638,400 B
  unsigned short* w2P    = (unsigned short*)(ws + 2687232);    // 6,553,600 B
  unsigned short* w3P    = (unsigned short*)(ws + 9240832);    // 6,553,600 B
  unsigned short* w4P    = (unsigned short*)(ws + 15794432);   // 1,228,800 B
  float* biasP           = (float*)(ws + 17023232);            //   163,200 B
  float* rewardWS        = (float*)(ws + 17186432);            // 1,638,400 B
  // total ws use: 18,824,832 B

  k_pack<<<1716, 256, 0, stream>>>(state, action, W1, W2, W3, W4, b1, b2, b3, b4,
                                   flag, saP, w1P, w2P, w3P, w4P, biasP);
  k_mlp<<<dim3(128, 50), 256, 0, stream>>>(saP, w1P, w2P, w3P, w4P, biasP, flag,
                                           rewardWS, d_out);
  k_reward<<<(NB * NE + 255) / 256, 256, 0, stream>>>(rewardWS, flag, d_out);
}

// Round 3
// 252.828 us; speedup vs baseline: 1.5574x; 1.5574x over previous
//
#include <hip/hip_runtime.h>

// ---------------------------------------------------------------------------
// EnsembleTransitionMLP: fused 4-layer MLP over 50 ensembles, bf16 MFMA.
// Round 8 (revert R7's launch-bounds; keep XCD swizzle):
//  - R7's __launch_bounds__(256,5) made the compiler cap VGPR at 48 < the
//    64 accumulator floats -> scratch spills (WRITE 601MB, FETCH 281MB,
//    2x slowdown). Back to (256,4): VGPR=64, zero spill (R6-proven).
//  - XCD-aware block swizzle kept: lid=(y*128+x); swz=(lid%8)*800+lid/8
//    gives each XCD a contiguous ~6.25-ensemble window (~2.2MB packed
//    panels, L2-resident). R6 measured FETCH=66MB = 4x the 16MB packed
//    weights from round-robin dispatch; swizzle should cut it to ~25-45MB.
//  - 4 blocks/CU x 32KB LDS = 128KB; 16 waves/CU.
// Fragment layouts (16x16x32 bf16, same as R2-R7):
//   A: lane l holds A[m=l&15][k=(l>>4)*8+j]   (weights as W^T)
//   B: lane l holds B[k=(l>>4)*8+j][n=l&15]   (h^T: k=feat, n=batch)
//   C/D: lane l, reg r: feat=(l>>4)*4+r, batch=l&15
// ---------------------------------------------------------------------------

typedef __attribute__((ext_vector_type(8))) short short8;
typedef __attribute__((ext_vector_type(4))) float floatx4;

#define NE 50
#define NB 8192
#define OUT_NS_ELEMS (NB * NE * 32)
#define OSTRIDE 48  // shorts; 96B = 16B-aligned rows for b128 reads

__device__ __forceinline__ unsigned short f2bf_rne(float x) {
  unsigned u = __float_as_uint(x);
  u += 0x7fffu + ((u >> 16) & 1u);
  return (unsigned short)(u >> 16);
}
__device__ __forceinline__ float bf2f(unsigned short b) {
  return __uint_as_float(((unsigned)b) << 16);
}
__device__ __forceinline__ floatx4 mfma16(short8 a, short8 b, floatx4 c) {
  return __builtin_amdgcn_mfma_f32_16x16x32_bf16(a, b, c, 0, 0, 0);
}
// pack two f32 -> one dword of bf16 pair, round-half-up
__device__ __forceinline__ unsigned pack_bf2(float lo, float hi) {
  unsigned u0 = __float_as_uint(lo) + 0x8000u;
  unsigned u1 = __float_as_uint(hi) + 0x8000u;
  return __builtin_amdgcn_perm(u1, u0, 0x07060302u);  // [u0.hi16, u1.hi16]
}

__device__ __forceinline__ unsigned short load_bf(const void* p, long i, bool isbf) {
  if (isbf) return ((const unsigned short*)p)[i];
  return f2bf_rne(((const float*)p)[i]);
}
__device__ __forceinline__ float load_f(const void* p, long i, bool isbf) {
  if (isbf) return bf2f(((const unsigned short*)p)[i]);
  return ((const float*)p)[i];
}

// ---------------- mega pack (R3 layout; detection folded in) ----------------
// W pack layout per ensemble (B-fragment order):
//   elt = (((kt*NT + nt)*4 + kb)*16 + ni)*8 + j ; k = kt*32+kb*8+j ; n = nt*16+ni
__device__ void pack_w_panel(const void* __restrict__ src, unsigned short* __restrict__ dst,
                             bool isbf, int e, int kt, int K, int N, int NT, int perE,
                             unsigned short* lds) {
  const int t = threadIdx.x;
  const int Npad = NT * 16;
  const int NP = Npad + 10;
  for (int idx = t; idx < 32 * Npad; idx += 256) {
    int r = idx / Npad, c = idx - r * Npad;
    int k = kt * 32 + r;
    unsigned short v = 0;
    if (k < K && c < N) v = load_bf(src, (long)(e * K + k) * N + c, isbf);
    lds[r * NP + c] = v;
  }
  __syncthreads();
  for (int u = t; u < NT * 64; u += 256) {
    int nt = u >> 6, kb = (u >> 4) & 3, ni = u & 15;
    int n = nt * 16 + ni;
    unsigned v[4];
#pragma unroll
    for (int p = 0; p < 4; ++p) {
      unsigned lo = lds[(kb * 8 + 2 * p) * NP + n];
      unsigned hi = lds[(kb * 8 + 2 * p + 1) * NP + n];
      v[p] = lo | (hi << 16);
    }
    long off = (long)e * perE + ((long)((kt * NT + nt) * 64 + kb * 16 + ni)) * 8;
    *(uint4*)(dst + off) = make_uint4(v[0], v[1], v[2], v[3]);
  }
}

__global__ void k_pack(const void* __restrict__ state, const void* __restrict__ action,
                       const void* __restrict__ W1, const void* __restrict__ W2,
                       const void* __restrict__ W3, const void* __restrict__ W4,
                       const void* __restrict__ b1, const void* __restrict__ b2,
                       const void* __restrict__ b3, const void* __restrict__ b4,
                       int* __restrict__ flag,
                       unsigned short* __restrict__ saP, unsigned short* __restrict__ w1P,
                       unsigned short* __restrict__ w2P, unsigned short* __restrict__ w3P,
                       unsigned short* __restrict__ w4P, float* __restrict__ biasP) {
  __shared__ unsigned short lds[32 * 266];  // 17,024 B
  __shared__ int s_bad;
  const int t = threadIdx.x;
  // --- inline dtype detection: 64 strided samples of W2 raw words ---
  if (t == 0) s_bad = 0;
  __syncthreads();
  if (t < 64) {
    unsigned word = ((const unsigned*)W2)[(long)(t * 32) * 797];
    unsigned short lo = (unsigned short)(word & 0xFFFFu);
    float f = bf2f(lo);
    if (!(fabsf(f) < 16.0f) || lo == 0) s_bad = 1;
  }
  __syncthreads();
  const bool isbf = (s_bad == 0);
  if (blockIdx.x == 0 && t == 0) *flag = isbf ? 1 : 0;

  const int b = blockIdx.x;
  if (b < 400) {
    pack_w_panel(W2, w2P, isbf, b >> 3, b & 7, 256, 256, 16, 65536, lds);
  } else if (b < 800) {
    int bb = b - 400;
    pack_w_panel(W3, w3P, isbf, bb >> 3, bb & 7, 256, 256, 16, 65536, lds);
  } else if (b < 900) {
    int bb = b - 800;
    pack_w_panel(W1, w1P, isbf, bb >> 1, bb & 1, 40, 256, 16, 16384, lds);
  } else if (b < 1300) {
    int bb = b - 900;
    pack_w_panel(W4, w4P, isbf, bb >> 3, bb & 7, 256, 33, 3, 12288, lds);
  } else if (b < 1556) {
    // sa pack (B-frag units): addr(batch=mt*16+mi, k=kb*8+j) =
    //   (mt*128 + kb*16 + mi)*8 + j   (K padded 40->64)
    int u = (b - 1300) * 256 + threadIdx.x;  // < 65536
    int mi = u & 15, kb = (u >> 4) & 7, mt = u >> 7;
    int row = mt * 16 + mi;
    unsigned v[4] = {0u, 0u, 0u, 0u};
    if (kb < 4) {
#pragma unroll
      for (int p = 0; p < 4; ++p) {
        unsigned lo = load_bf(state, (long)row * 32 + kb * 8 + 2 * p, isbf);
        unsigned hi = load_bf(state, (long)row * 32 + kb * 8 + 2 * p + 1, isbf);
        v[p] = lo | (hi << 16);
      }
    } else if (kb == 4) {
#pragma unroll
      for (int p = 0; p < 4; ++p) {
        unsigned lo = load_bf(action, (long)row * 8 + 2 * p, isbf);
        unsigned hi = load_bf(action, (long)row * 8 + 2 * p + 1, isbf);
        v[p] = lo | (hi << 16);
      }
    }
    *(uint4*)(saP + (long)u * 8) = make_uint4(v[0], v[1], v[2], v[3]);
  } else {
    // bias: per e: [b1(256)][b2(256)][b3(256)][b4(48 zero-padded)]
    int gid = (b - 1556) * 256 + threadIdx.x;
    if (gid < NE * 816) {
      int e = gid / 816, r = gid - e * 816;
      float v = 0.0f;
      if (r < 256)      v = load_f(b1, e * 256 + r,         isbf);
      else if (r < 512) v = load_f(b2, e * 256 + (r - 256), isbf);
      else if (r < 768) v = load_f(b3, e * 256 + (r - 512), isbf);
      else { int q = r - 768; if (q < 33) v = load_f(b4, e * 33 + q, isbf); }
      biasP[gid] = v;
    }
  }
}

// ---------------- fused MLP ----------------
// hT in LDS (32KB), B-frag units for BM=64:
//   short addr(k,b) = ((k>>5)*4 + (b>>4))*512 + ((k>>3)&3)*128 + (b&15)*8 + (k&7)
// B-frag read (kt, bt): 16B at ((kt*4 + bt)*64 + l)*8.

__device__ __forceinline__ void store_tile16(const floatx4& a4, unsigned short* hT,
                                             int FT, int BT, int li, int g) {
  int k0 = FT * 16 + g * 4;
  unsigned d0 = pack_bf2(fmaxf(a4[0], 0.0f), fmaxf(a4[1], 0.0f));
  unsigned d1 = pack_bf2(fmaxf(a4[2], 0.0f), fmaxf(a4[3], 0.0f));
  int addr = ((k0 >> 5) * 4 + BT) * 512 + ((k0 >> 3) & 3) * 128 + li * 8 + (k0 & 7);
  *(unsigned long long*)(hT + addr) =
      (unsigned long long)d0 | ((unsigned long long)d1 << 32);
}

// wave wf owns feats [wf*64, wf*64+64) x all 64 batch: acc[4 ftiles][4 btiles]
__device__ __forceinline__ void hidden_layer(const unsigned short* __restrict__ wp,
                                             const float* __restrict__ br,
                                             unsigned short* hT,
                                             int wf, int l, int li, int g) {
  floatx4 acc[4][4];
#pragma unroll
  for (int ot = 0; ot < 4; ++ot) {
    const float4 bq = *(const float4*)(br + wf * 64 + ot * 16 + g * 4);
    floatx4 iv = {bq.x, bq.y, bq.z, bq.w};
#pragma unroll
    for (int bt = 0; bt < 4; ++bt) acc[ot][bt] = iv;
  }
#pragma unroll
  for (int kt = 0; kt < 8; ++kt) {
    short8 a[4];
#pragma unroll
    for (int ot = 0; ot < 4; ++ot)
      a[ot] = *(const short8*)(wp + (long)((kt * 16 + wf * 4 + ot) * 64 + l) * 8);
#pragma unroll
    for (int bt = 0; bt < 4; ++bt) {
      short8 b = *(const short8*)(hT + ((kt * 4 + bt) * 64 + l) * 8);
#pragma unroll
      for (int ot = 0; ot < 4; ++ot)
        acc[ot][bt] = mfma16(a[ot], b, acc[ot][bt]);
    }
  }
  __syncthreads();  // all reads of hT done before in-place overwrite
#pragma unroll
  for (int ot = 0; ot < 4; ++ot)
#pragma unroll
    for (int bt = 0; bt < 4; ++bt)
      store_tile16(acc[ot][bt], hT, wf * 4 + ot, bt, li, g);
  __syncthreads();
}

__global__ __launch_bounds__(256, 4) void k_mlp(
    const unsigned short* __restrict__ sa,
    const unsigned short* __restrict__ w1,
    const unsigned short* __restrict__ w2,
    const unsigned short* __restrict__ w3,
    const unsigned short* __restrict__ w4,
    const float* __restrict__ bias,
    const int* __restrict__ flag,
    float* __restrict__ rewardWS,
    void* __restrict__ outp) {
  __shared__ __attribute__((aligned(16))) unsigned short hT[16384];  // 32 KB
  const int tid = threadIdx.x;
  const int wf = tid >> 6, l = tid & 63, li = l & 15, g = l >> 4;

  // XCD-aware swizzle: hw assigns linear id round-robin (xcd = lid % 8).
  // swz = (lid%8)*800 + lid/8 gives each XCD a contiguous block range =>
  // contiguous ~6.25-ensemble window whose packed panels fit its 4MB L2.
  // 6400 % 8 == 0 -> bijective.
  const int lid = blockIdx.y * 128 + blockIdx.x;
  const int swz = (lid & 7) * 800 + (lid >> 3);
  const int e  = swz >> 7;         // ensemble
  const int bb = swz & 127;        // 64-row batch tile (128 tiles)

  const float* brow = bias + e * 816;
  const bool isbf = (*flag != 0);

  // ---- layer 1: W1^T(256x64) * sa^T(64x64) -> h1^T in LDS ----
  {
    floatx4 acc[4][4];
#pragma unroll
    for (int ot = 0; ot < 4; ++ot) {
      const float4 bq = *(const float4*)(brow + wf * 64 + ot * 16 + g * 4);
      floatx4 iv = {bq.x, bq.y, bq.z, bq.w};
#pragma unroll
      for (int bt = 0; bt < 4; ++bt) acc[ot][bt] = iv;
    }
#pragma unroll
    for (int kt = 0; kt < 2; ++kt) {
      short8 a[4];
#pragma unroll
      for (int ot = 0; ot < 4; ++ot)
        a[ot] = *(const short8*)(w1 + (long)e * 16384 +
                                 (long)((kt * 16 + wf * 4 + ot) * 64 + l) * 8);
#pragma unroll
      for (int bt = 0; bt < 4; ++bt) {
        short8 b = *(const short8*)(sa + (long)((bb * 4 + bt) * 128 + kt * 64 + l) * 8);
#pragma unroll
        for (int ot = 0; ot < 4; ++ot)
          acc[ot][bt] = mfma16(a[ot], b, acc[ot][bt]);
      }
    }
#pragma unroll
    for (int ot = 0; ot < 4; ++ot)
#pragma unroll
      for (int bt = 0; bt < 4; ++bt)
        store_tile16(acc[ot][bt], hT, wf * 4 + ot, bt, li, g);
    __syncthreads();
  }

  // ---- layers 2, 3 ----
  hidden_layer(w2 + (long)e * 65536, brow + 256, hT, wf, l, li, g);
  hidden_layer(w3 + (long)e * 65536, brow + 512, hT, wf, l, li, g);

  // ---- layer 4: W4^T(48x256) * h3^T(256x64); wave wf owns btile wf ----
  const float* brow4 = brow + 768;
  floatx4 acc4[3];
#pragma unroll
  for (int ft = 0; ft < 3; ++ft) {
    const float4 bq = *(const float4*)(brow4 + ft * 16 + g * 4);
    floatx4 iv = {bq.x, bq.y, bq.z, bq.w};
    acc4[ft] = iv;
  }
#pragma unroll
  for (int kt = 0; kt < 8; ++kt) {
    short8 a[3];
#pragma unroll
    for (int ft = 0; ft < 3; ++ft)
      a[ft] = *(const short8*)(w4 + (long)e * 12288 + (long)((kt * 3 + ft) * 64 + l) * 8);
    short8 b = *(const short8*)(hT + ((kt * 4 + wf) * 64 + l) * 8);
#pragma unroll
    for (int ft = 0; ft < 3; ++ft)
      acc4[ft] = mfma16(a[ft], b, acc4[ft]);
  }

  // reward (feat 32 = ft2, g==0, reg 0) -> staged coalesced into ws[e][batch]
  if (g == 0) {
    rewardWS[(long)e * NB + bb * 64 + wf * 16 + li] = acc4[2][0];
  }

  __syncthreads();  // all hT reads done; reuse hT as output staging buffer
  // stage out^T tiles -> osta[batch][feat] (bf16, stride OSTRIDE)
#pragma unroll
  for (int ft = 0; ft < 2; ++ft) {
    int batch = wf * 16 + li;
    unsigned d0 = pack_bf2(acc4[ft][0], acc4[ft][1]);
    unsigned d1 = pack_bf2(acc4[ft][2], acc4[ft][3]);
    *(unsigned long long*)(hT + batch * OSTRIDE + ft * 16 + g * 4) =
        (unsigned long long)d0 | ((unsigned long long)d1 << 32);
  }
  __syncthreads();

  // coalesced store: full 64B line per (batch,e)
  if (isbf) {
    unsigned short* o16 = (unsigned short*)outp;
    int batch = tid >> 2;
    int chunk = tid & 3;  // 8 shorts each
    uint4 v = *(const uint4*)(hT + batch * OSTRIDE + chunk * 8);
    *(uint4*)(o16 + ((long)(bb * 64 + batch) * NE + e) * 32 + chunk * 8) = v;
  } else {
    float* o32 = (float*)outp;
#pragma unroll
    for (int p = 0; p < 2; ++p) {
      int idx = p * 256 + tid;
      int batch = idx >> 3;
      int chunk = idx & 7;  // 4 floats each
      const unsigned short* s = hT + batch * OSTRIDE + chunk * 4;
      *(float4*)(o32 + ((long)(bb * 64 + batch) * NE + e) * 32 + chunk * 4) =
          make_float4(bf2f(s[0]), bf2f(s[1]), bf2f(s[2]), bf2f(s[3]));
    }
  }
}

// ---------------- reward transpose epilogue ----------------
__global__ void k_reward(const float* __restrict__ rw, const int* __restrict__ flag,
                         void* __restrict__ outp) {
  int id = blockIdx.x * 256 + threadIdx.x;
  if (id >= NB * NE) return;
  int b = id / NE, e = id - b * NE;
  float v = rw[(long)e * NB + b];
  if (*flag != 0) {
    unsigned u = __float_as_uint(v) + 0x8000u;
    ((unsigned short*)outp)[OUT_NS_ELEMS + id] = (unsigned short)(u >> 16);
  } else {
    ((float*)outp)[OUT_NS_ELEMS + id] = v;
  }
}

// ---------------------------------------------------------------------------
extern "C" void kernel_launch(void* const* d_in, const int* in_sizes, int n_in,
                              void* d_out, int out_size, void* d_ws, size_t ws_size,
                              hipStream_t stream) {
  const void* state  = d_in[0];
  const void* action = d_in[1];
  const void* W1 = d_in[2];
  const void* b1 = d_in[3];
  const void* W2 = d_in[4];
  const void* b2 = d_in[5];
  const void* W3 = d_in[6];
  const void* b3 = d_in[7];
  const void* W4 = d_in[8];
  const void* b4 = d_in[9];
  (void)in_sizes; (void)n_in; (void)out_size; (void)ws_size;

  char* ws = (char*)d_ws;
  int* flag              = (int*)(ws + 0);
  unsigned short* saP    = (unsigned short*)(ws + 256);        // 1,048,576 B
  unsigned short* w1P    = (unsigned short*)(ws + 1048832);    // 1,638,400 B
  unsigned short* w2P    = (unsigned short*)(ws + 2687232);    // 6,553,600 B
  unsigned short* w3P    = (unsigned short*)(ws + 9240832);    // 6,553,600 B
  unsigned short* w4P    = (unsigned short*)(ws + 15794432);   // 1,228,800 B
  float* biasP           = (float*)(ws + 17023232);            //   163,200 B
  float* rewardWS        = (float*)(ws + 17186432);            // 1,638,400 B
  // total ws use: 18,824,832 B

  k_pack<<<1716, 256, 0, stream>>>(state, action, W1, W2, W3, W4, b1, b2, b3, b4,
                                   flag, saP, w1P, w2P, w3P, w4P, biasP);
  k_mlp<<<dim3(128, 50), 256, 0, stream>>>(saP, w1P, w2P, w3P, w4P, biasP, flag,
                                           rewardWS, d_out);
  k_reward<<<(NB * NE + 255) / 256, 256, 0, stream>>>(rewardWS, flag, d_out);
}

// Round 4
// 248.106 us; speedup vs baseline: 1.5870x; 1.0190x over previous
//
#include <hip/hip_runtime.h>

// ---------------------------------------------------------------------------
// EnsembleTransitionMLP: fused 4-layer MLP over 50 ensembles, bf16 MFMA.
// Round 9 (hide a-load latency; cheap detection):
//  - R8 confirmed swizzle works (FETCH 66->15.9MB = packed-weight footprint)
//    but time unchanged -> k_mlp is latency/issue-bound, not BW-bound.
//  - Reg math: 64 VGPR + 64 AGPR = exactly the (256,4) 128-reg cap -> no
//    prefetch possible -> each kt stalls ~250cyc on 4 global a-loads before
//    310cyc of MFMA (duty ~50%, MfmaUtil 41%). NOW: depth-1 a-frag register
//    ring (+16 VGPR) under __launch_bounds__(256,3) (cap 170): global
//    latency hides under MFMA; 3 waves/SIMD x ~85% duty > 4 x 50%.
//  - Detection preamble: R6 folded a 64-lane STRIDED (102KB apart) W2
//    sample into every k_pack block (+25us vs R5's rest-time). Now samples
//    64 CONTIGUOUS words (one 256B region, L2-broadcast). Same stats:
//    P(f32 slips) ~ 0.51^64 ~ 2e-19.
//  - XCD swizzle kept (weights read once from HBM).
// Fragment layouts (16x16x32 bf16, same as R2-R8):
//   A: lane l holds A[m=l&15][k=(l>>4)*8+j]   (weights as W^T)
//   B: lane l holds B[k=(l>>4)*8+j][n=l&15]   (h^T: k=feat, n=batch)
//   C/D: lane l, reg r: feat=(l>>4)*4+r, batch=l&15
// ---------------------------------------------------------------------------

typedef __attribute__((ext_vector_type(8))) short short8;
typedef __attribute__((ext_vector_type(4))) float floatx4;

#define NE 50
#define NB 8192
#define OUT_NS_ELEMS (NB * NE * 32)
#define OSTRIDE 48  // shorts; 96B = 16B-aligned rows for b128 reads

__device__ __forceinline__ unsigned short f2bf_rne(float x) {
  unsigned u = __float_as_uint(x);
  u += 0x7fffu + ((u >> 16) & 1u);
  return (unsigned short)(u >> 16);
}
__device__ __forceinline__ float bf2f(unsigned short b) {
  return __uint_as_float(((unsigned)b) << 16);
}
__device__ __forceinline__ floatx4 mfma16(short8 a, short8 b, floatx4 c) {
  return __builtin_amdgcn_mfma_f32_16x16x32_bf16(a, b, c, 0, 0, 0);
}
// pack two f32 -> one dword of bf16 pair, round-half-up
__device__ __forceinline__ unsigned pack_bf2(float lo, float hi) {
  unsigned u0 = __float_as_uint(lo) + 0x8000u;
  unsigned u1 = __float_as_uint(hi) + 0x8000u;
  return __builtin_amdgcn_perm(u1, u0, 0x07060302u);  // [u0.hi16, u1.hi16]
}

__device__ __forceinline__ unsigned short load_bf(const void* p, long i, bool isbf) {
  if (isbf) return ((const unsigned short*)p)[i];
  return f2bf_rne(((const float*)p)[i]);
}
__device__ __forceinline__ float load_f(const void* p, long i, bool isbf) {
  if (isbf) return bf2f(((const unsigned short*)p)[i]);
  return ((const float*)p)[i];
}

// ---------------- mega pack (R3 layout; cheap detection) ----------------
// W pack layout per ensemble (B-fragment order):
//   elt = (((kt*NT + nt)*4 + kb)*16 + ni)*8 + j ; k = kt*32+kb*8+j ; n = nt*16+ni
__device__ void pack_w_panel(const void* __restrict__ src, unsigned short* __restrict__ dst,
                             bool isbf, int e, int kt, int K, int N, int NT, int perE,
                             unsigned short* lds) {
  const int t = threadIdx.x;
  const int Npad = NT * 16;
  const int NP = Npad + 10;
  for (int idx = t; idx < 32 * Npad; idx += 256) {
    int r = idx / Npad, c = idx - r * Npad;
    int k = kt * 32 + r;
    unsigned short v = 0;
    if (k < K && c < N) v = load_bf(src, (long)(e * K + k) * N + c, isbf);
    lds[r * NP + c] = v;
  }
  __syncthreads();
  for (int u = t; u < NT * 64; u += 256) {
    int nt = u >> 6, kb = (u >> 4) & 3, ni = u & 15;
    int n = nt * 16 + ni;
    unsigned v[4];
#pragma unroll
    for (int p = 0; p < 4; ++p) {
      unsigned lo = lds[(kb * 8 + 2 * p) * NP + n];
      unsigned hi = lds[(kb * 8 + 2 * p + 1) * NP + n];
      v[p] = lo | (hi << 16);
    }
    long off = (long)e * perE + ((long)((kt * NT + nt) * 64 + kb * 16 + ni)) * 8;
    *(uint4*)(dst + off) = make_uint4(v[0], v[1], v[2], v[3]);
  }
}

__global__ void k_pack(const void* __restrict__ state, const void* __restrict__ action,
                       const void* __restrict__ W1, const void* __restrict__ W2,
                       const void* __restrict__ W3, const void* __restrict__ W4,
                       const void* __restrict__ b1, const void* __restrict__ b2,
                       const void* __restrict__ b3, const void* __restrict__ b4,
                       int* __restrict__ flag,
                       unsigned short* __restrict__ saP, unsigned short* __restrict__ w1P,
                       unsigned short* __restrict__ w2P, unsigned short* __restrict__ w3P,
                       unsigned short* __restrict__ w4P, float* __restrict__ biasP) {
  __shared__ unsigned short lds[32 * 266];  // 17,024 B
  __shared__ int s_bad;
  const int t = threadIdx.x;
  // --- inline dtype detection: 64 CONTIGUOUS W2 words (one 256B region;
  //     L2-broadcast across blocks; no strided TLB walk) ---
  if (t == 0) s_bad = 0;
  __syncthreads();
  if (t < 64) {
    unsigned word = ((const unsigned*)W2)[t];
    unsigned short lo = (unsigned short)(word & 0xFFFFu);
    float f = bf2f(lo);
    if (!(fabsf(f) < 16.0f) || lo == 0) s_bad = 1;
  }
  __syncthreads();
  const bool isbf = (s_bad == 0);
  if (blockIdx.x == 0 && t == 0) *flag = isbf ? 1 : 0;

  const int b = blockIdx.x;
  if (b < 400) {
    pack_w_panel(W2, w2P, isbf, b >> 3, b & 7, 256, 256, 16, 65536, lds);
  } else if (b < 800) {
    int bb = b - 400;
    pack_w_panel(W3, w3P, isbf, bb >> 3, bb & 7, 256, 256, 16, 65536, lds);
  } else if (b < 900) {
    int bb = b - 800;
    pack_w_panel(W1, w1P, isbf, bb >> 1, bb & 1, 40, 256, 16, 16384, lds);
  } else if (b < 1300) {
    int bb = b - 900;
    pack_w_panel(W4, w4P, isbf, bb >> 3, bb & 7, 256, 33, 3, 12288, lds);
  } else if (b < 1556) {
    // sa pack (B-frag units): addr(batch=mt*16+mi, k=kb*8+j) =
    //   (mt*128 + kb*16 + mi)*8 + j   (K padded 40->64)
    int u = (b - 1300) * 256 + threadIdx.x;  // < 65536
    int mi = u & 15, kb = (u >> 4) & 7, mt = u >> 7;
    int row = mt * 16 + mi;
    unsigned v[4] = {0u, 0u, 0u, 0u};
    if (kb < 4) {
#pragma unroll
      for (int p = 0; p < 4; ++p) {
        unsigned lo = load_bf(state, (long)row * 32 + kb * 8 + 2 * p, isbf);
        unsigned hi = load_bf(state, (long)row * 32 + kb * 8 + 2 * p + 1, isbf);
        v[p] = lo | (hi << 16);
      }
    } else if (kb == 4) {
#pragma unroll
      for (int p = 0; p < 4; ++p) {
        unsigned lo = load_bf(action, (long)row * 8 + 2 * p, isbf);
        unsigned hi = load_bf(action, (long)row * 8 + 2 * p + 1, isbf);
        v[p] = lo | (hi << 16);
      }
    }
    *(uint4*)(saP + (long)u * 8) = make_uint4(v[0], v[1], v[2], v[3]);
  } else {
    // bias: per e: [b1(256)][b2(256)][b3(256)][b4(48 zero-padded)]
    int gid = (b - 1556) * 256 + threadIdx.x;
    if (gid < NE * 816) {
      int e = gid / 816, r = gid - e * 816;
      float v = 0.0f;
      if (r < 256)      v = load_f(b1, e * 256 + r,         isbf);
      else if (r < 512) v = load_f(b2, e * 256 + (r - 256), isbf);
      else if (r < 768) v = load_f(b3, e * 256 + (r - 512), isbf);
      else { int q = r - 768; if (q < 33) v = load_f(b4, e * 33 + q, isbf); }
      biasP[gid] = v;
    }
  }
}

// ---------------- fused MLP ----------------
// hT in LDS (32KB), B-frag units for BM=64:
//   short addr(k,b) = ((k>>5)*4 + (b>>4))*512 + ((k>>3)&3)*128 + (b&15)*8 + (k&7)
// B-frag read (kt, bt): 16B at ((kt*4 + bt)*64 + l)*8.

__device__ __forceinline__ void store_tile16(const floatx4& a4, unsigned short* hT,
                                             int FT, int BT, int li, int g) {
  int k0 = FT * 16 + g * 4;
  unsigned d0 = pack_bf2(fmaxf(a4[0], 0.0f), fmaxf(a4[1], 0.0f));
  unsigned d1 = pack_bf2(fmaxf(a4[2], 0.0f), fmaxf(a4[3], 0.0f));
  int addr = ((k0 >> 5) * 4 + BT) * 512 + ((k0 >> 3) & 3) * 128 + li * 8 + (k0 & 7);
  *(unsigned long long*)(hT + addr) =
      (unsigned long long)d0 | ((unsigned long long)d1 << 32);
}

// wave wf owns feats [wf*64, wf*64+64) x all 64 batch: acc[4 ftiles][4 btiles]
// depth-1 a-frag prefetch ring: an[] loads for kt+1 issue before kt's MFMAs.
__device__ __forceinline__ void hidden_layer(const unsigned short* __restrict__ wp,
                                             const float* __restrict__ br,
                                             unsigned short* hT,
                                             int wf, int l, int li, int g) {
  floatx4 acc[4][4];
#pragma unroll
  for (int ot = 0; ot < 4; ++ot) {
    const float4 bq = *(const float4*)(br + wf * 64 + ot * 16 + g * 4);
    floatx4 iv = {bq.x, bq.y, bq.z, bq.w};
#pragma unroll
    for (int bt = 0; bt < 4; ++bt) acc[ot][bt] = iv;
  }
  short8 a[4], an[4];
#pragma unroll
  for (int ot = 0; ot < 4; ++ot)
    a[ot] = *(const short8*)(wp + (long)((wf * 4 + ot) * 64 + l) * 8);
#pragma unroll
  for (int kt = 0; kt < 8; ++kt) {
    if (kt < 7) {
#pragma unroll
      for (int ot = 0; ot < 4; ++ot)
        an[ot] = *(const short8*)(wp + (long)(((kt + 1) * 16 + wf * 4 + ot) * 64 + l) * 8);
    }
#pragma unroll
    for (int bt = 0; bt < 4; ++bt) {
      short8 b = *(const short8*)(hT + ((kt * 4 + bt) * 64 + l) * 8);
#pragma unroll
      for (int ot = 0; ot < 4; ++ot)
        acc[ot][bt] = mfma16(a[ot], b, acc[ot][bt]);
    }
    if (kt < 7) {
#pragma unroll
      for (int ot = 0; ot < 4; ++ot) a[ot] = an[ot];
    }
  }
  __syncthreads();  // all reads of hT done before in-place overwrite
#pragma unroll
  for (int ot = 0; ot < 4; ++ot)
#pragma unroll
    for (int bt = 0; bt < 4; ++bt)
      store_tile16(acc[ot][bt], hT, wf * 4 + ot, bt, li, g);
  __syncthreads();
}

__global__ __launch_bounds__(256, 3) void k_mlp(
    const unsigned short* __restrict__ sa,
    const unsigned short* __restrict__ w1,
    const unsigned short* __restrict__ w2,
    const unsigned short* __restrict__ w3,
    const unsigned short* __restrict__ w4,
    const float* __restrict__ bias,
    const int* __restrict__ flag,
    float* __restrict__ rewardWS,
    void* __restrict__ outp) {
  __shared__ __attribute__((aligned(16))) unsigned short hT[16384];  // 32 KB
  const int tid = threadIdx.x;
  const int wf = tid >> 6, l = tid & 63, li = l & 15, g = l >> 4;

  // XCD-aware swizzle: hw assigns linear id round-robin (xcd = lid % 8).
  // swz = (lid%8)*800 + lid/8 gives each XCD a contiguous block range =>
  // contiguous ~6.25-ensemble window whose packed panels fit its 4MB L2.
  // 6400 % 8 == 0 -> bijective. (R8: FETCH 66->15.9MB, confirmed.)
  const int lid = blockIdx.y * 128 + blockIdx.x;
  const int swz = (lid & 7) * 800 + (lid >> 3);
  const int e  = swz >> 7;         // ensemble
  const int bb = swz & 127;        // 64-row batch tile (128 tiles)

  const float* brow = bias + e * 816;
  const bool isbf = (*flag != 0);

  // ---- layer 1: W1^T(256x64) * sa^T(64x64) -> h1^T in LDS ----
  {
    floatx4 acc[4][4];
#pragma unroll
    for (int ot = 0; ot < 4; ++ot) {
      const float4 bq = *(const float4*)(brow + wf * 64 + ot * 16 + g * 4);
      floatx4 iv = {bq.x, bq.y, bq.z, bq.w};
#pragma unroll
      for (int bt = 0; bt < 4; ++bt) acc[ot][bt] = iv;
    }
#pragma unroll
    for (int kt = 0; kt < 2; ++kt) {
      short8 a[4];
#pragma unroll
      for (int ot = 0; ot < 4; ++ot)
        a[ot] = *(const short8*)(w1 + (long)e * 16384 +
                                 (long)((kt * 16 + wf * 4 + ot) * 64 + l) * 8);
#pragma unroll
      for (int bt = 0; bt < 4; ++bt) {
        short8 b = *(const short8*)(sa + (long)((bb * 4 + bt) * 128 + kt * 64 + l) * 8);
#pragma unroll
        for (int ot = 0; ot < 4; ++ot)
          acc[ot][bt] = mfma16(a[ot], b, acc[ot][bt]);
      }
    }
#pragma unroll
    for (int ot = 0; ot < 4; ++ot)
#pragma unroll
      for (int bt = 0; bt < 4; ++bt)
        store_tile16(acc[ot][bt], hT, wf * 4 + ot, bt, li, g);
    __syncthreads();
  }

  // ---- layers 2, 3 ----
  hidden_layer(w2 + (long)e * 65536, brow + 256, hT, wf, l, li, g);
  hidden_layer(w3 + (long)e * 65536, brow + 512, hT, wf, l, li, g);

  // ---- layer 4: W4^T(48x256) * h3^T(256x64); wave wf owns btile wf ----
  const float* brow4 = brow + 768;
  floatx4 acc4[3];
#pragma unroll
  for (int ft = 0; ft < 3; ++ft) {
    const float4 bq = *(const float4*)(brow4 + ft * 16 + g * 4);
    floatx4 iv = {bq.x, bq.y, bq.z, bq.w};
    acc4[ft] = iv;
  }
  {
    short8 a[3], an[3];
#pragma unroll
    for (int ft = 0; ft < 3; ++ft)
      a[ft] = *(const short8*)(w4 + (long)e * 12288 + (long)(ft * 64 + l) * 8);
#pragma unroll
    for (int kt = 0; kt < 8; ++kt) {
      if (kt < 7) {
#pragma unroll
        for (int ft = 0; ft < 3; ++ft)
          an[ft] = *(const short8*)(w4 + (long)e * 12288 +
                                    (long)(((kt + 1) * 3 + ft) * 64 + l) * 8);
      }
      short8 b = *(const short8*)(hT + ((kt * 4 + wf) * 64 + l) * 8);
#pragma unroll
      for (int ft = 0; ft < 3; ++ft)
        acc4[ft] = mfma16(a[ft], b, acc4[ft]);
      if (kt < 7) {
#pragma unroll
        for (int ft = 0; ft < 3; ++ft) a[ft] = an[ft];
      }
    }
  }

  // reward (feat 32 = ft2, g==0, reg 0) -> staged coalesced into ws[e][batch]
  if (g == 0) {
    rewardWS[(long)e * NB + bb * 64 + wf * 16 + li] = acc4[2][0];
  }

  __syncthreads();  // all hT reads done; reuse hT as output staging buffer
  // stage out^T tiles -> osta[batch][feat] (bf16, stride OSTRIDE)
#pragma unroll
  for (int ft = 0; ft < 2; ++ft) {
    int batch = wf * 16 + li;
    unsigned d0 = pack_bf2(acc4[ft][0], acc4[ft][1]);
    unsigned d1 = pack_bf2(acc4[ft][2], acc4[ft][3]);
    *(unsigned long long*)(hT + batch * OSTRIDE + ft * 16 + g * 4) =
        (unsigned long long)d0 | ((unsigned long long)d1 << 32);
  }
  __syncthreads();

  // coalesced store: full 64B line per (batch,e)
  if (isbf) {
    unsigned short* o16 = (unsigned short*)outp;
    int batch = tid >> 2;
    int chunk = tid & 3;  // 8 shorts each
    uint4 v = *(const uint4*)(hT + batch * OSTRIDE + chunk * 8);
    *(uint4*)(o16 + ((long)(bb * 64 + batch) * NE + e) * 32 + chunk * 8) = v;
  } else {
    float* o32 = (float*)outp;
#pragma unroll
    for (int p = 0; p < 2; ++p) {
      int idx = p * 256 + tid;
      int batch = idx >> 3;
      int chunk = idx & 7;  // 4 floats each
      const unsigned short* s = hT + batch * OSTRIDE + chunk * 4;
      *(float4*)(o32 + ((long)(bb * 64 + batch) * NE + e) * 32 + chunk * 4) =
          make_float4(bf2f(s[0]), bf2f(s[1]), bf2f(s[2]), bf2f(s[3]));
    }
  }
}

// ---------------- reward transpose epilogue ----------------
__global__ void k_reward(const float* __restrict__ rw, const int* __restrict__ flag,
                         void* __restrict__ outp) {
  int id = blockIdx.x * 256 + threadIdx.x;
  if (id >= NB * NE) return;
  int b = id / NE, e = id - b * NE;
  float v = rw[(long)e * NB + b];
  if (*flag != 0) {
    unsigned u = __float_as_uint(v) + 0x8000u;
    ((unsigned short*)outp)[OUT_NS_ELEMS + id] = (unsigned short)(u >> 16);
  } else {
    ((float*)outp)[OUT_NS_ELEMS + id] = v;
  }
}

// ---------------------------------------------------------------------------
extern "C" void kernel_launch(void* const* d_in, const int* in_sizes, int n_in,
                              void* d_out, int out_size, void* d_ws, size_t ws_size,
                              hipStream_t stream) {
  const void* state  = d_in[0];
  const void* action = d_in[1];
  const void* W1 = d_in[2];
  const void* b1 = d_in[3];
  const void* W2 = d_in[4];
  const void* b2 = d_in[5];
  const void* W3 = d_in[6];
  const void* b3 = d_in[7];
  const void* W4 = d_in[8];
  const void* b4 = d_in[9];
  (void)in_sizes; (void)n_in; (void)out_size; (void)ws_size;

  char* ws = (char*)d_ws;
  int* flag              = (int*)(ws + 0);
  unsigned short* saP    = (unsigned short*)(ws + 256);        // 1,048,576 B
  unsigned short* w1P    = (unsigned short*)(ws + 1048832);    // 1,638,400 B
  unsigned short* w2P    = (unsigned short*)(ws + 2687232);    // 6,553,600 B
  unsigned short* w3P    = (unsigned short*)(ws + 9240832);    // 6,553,600 B
  unsigned short* w4P    = (unsigned short*)(ws + 15794432);   // 1,228,800 B
  float* biasP           = (float*)(ws + 17023232);            //   163,200 B
  float* rewardWS        = (float*)(ws + 17186432);            // 1,638,400 B
  // total ws use: 18,824,832 B

  k_pack<<<1716, 256, 0, stream>>>(state, action, W1, W2, W3, W4, b1, b2, b3, b4,
                                   flag, saP, w1P, w2P, w3P, w4P, biasP);
  k_mlp<<<dim3(128, 50), 256, 0, stream>>>(saP, w1P, w2P, w3P, w4P, biasP, flag,
                                           rewardWS, d_out);
  k_reward<<<(NB * NE + 255) / 256, 256, 0, stream>>>(rewardWS, flag, d_out);
}

// Round 5
// 236.260 us; speedup vs baseline: 1.6666x; 1.0501x over previous
//
#include <hip/hip_runtime.h>

// ---------------------------------------------------------------------------
// EnsembleTransitionMLP: fused 4-layer MLP over 50 ensembles, bf16 MFMA.
// Round 10 (revert R9 ring; host-side dtype; vectorized pack):
//  - R9 post-mortem: depth-1 prefetch ring under (256,3) LOST 12us on k_mlp
//    (155 vs 143): 4 blocks/CU TLP already hid the a-load latency (R8's
//    FETCH 66->16MB with no time change proved it); trading a wave-slot
//    for ILP was net negative. k_mlp reverted to R8 exactly ((256,4),
//    no ring, XCD swizzle).
//  - dtype detection REMOVED: in_sizes[4] (W2 bytes) tells f32 vs bf16 on
//    the host (13,107,200 vs 6,553,600). No sampling kernel, no per-block
//    preamble (R6's preamble cost ~25us, R9's cheap one ~8us), no flag
//    load in any kernel.
//  - pack_w_panel load stage vectorized (G13): f32 -> float4 (16B/lane),
//    bf16 -> uint4 (8 shorts); scalar fallback only for W4 (N=33).
// Fragment layouts (16x16x32 bf16, same as R2-R9):
//   A: lane l holds A[m=l&15][k=(l>>4)*8+j]   (weights as W^T)
//   B: lane l holds B[k=(l>>4)*8+j][n=l&15]   (h^T: k=feat, n=batch)
//   C/D: lane l, reg r: feat=(l>>4)*4+r, batch=l&15
// ---------------------------------------------------------------------------

typedef __attribute__((ext_vector_type(8))) short short8;
typedef __attribute__((ext_vector_type(4))) float floatx4;

#define NE 50
#define NB 8192
#define OUT_NS_ELEMS (NB * NE * 32)
#define OSTRIDE 48  // shorts; 96B = 16B-aligned rows for b128 reads

__device__ __forceinline__ unsigned short f2bf_rne(float x) {
  unsigned u = __float_as_uint(x);
  u += 0x7fffu + ((u >> 16) & 1u);
  return (unsigned short)(u >> 16);
}
__device__ __forceinline__ float bf2f(unsigned short b) {
  return __uint_as_float(((unsigned)b) << 16);
}
__device__ __forceinline__ floatx4 mfma16(short8 a, short8 b, floatx4 c) {
  return __builtin_amdgcn_mfma_f32_16x16x32_bf16(a, b, c, 0, 0, 0);
}
// pack two f32 -> one dword of bf16 pair, round-half-up
__device__ __forceinline__ unsigned pack_bf2(float lo, float hi) {
  unsigned u0 = __float_as_uint(lo) + 0x8000u;
  unsigned u1 = __float_as_uint(hi) + 0x8000u;
  return __builtin_amdgcn_perm(u1, u0, 0x07060302u);  // [u0.hi16, u1.hi16]
}

__device__ __forceinline__ unsigned short load_bf(const void* p, long i, bool isbf) {
  if (isbf) return ((const unsigned short*)p)[i];
  return f2bf_rne(((const float*)p)[i]);
}
__device__ __forceinline__ float load_f(const void* p, long i, bool isbf) {
  if (isbf) return bf2f(((const unsigned short*)p)[i]);
  return ((const float*)p)[i];
}

// ---------------- mega pack (R3 layout; vectorized loads) ----------------
// W pack layout per ensemble (B-fragment order):
//   elt = (((kt*NT + nt)*4 + kb)*16 + ni)*8 + j ; k = kt*32+kb*8+j ; n = nt*16+ni
__device__ void pack_w_panel(const void* __restrict__ src, unsigned short* __restrict__ dst,
                             bool isbf, int e, int kt, int K, int N, int NT, int perE,
                             unsigned short* lds) {
  const int t = threadIdx.x;
  const int Npad = NT * 16;
  const int NP = Npad + 10;
  if (!isbf && N == Npad) {
    // f32, full-width rows (W1/W2/W3: N=256): float4 loads, 4 bf16/lane/iter
    const int nq = Npad >> 2;
    for (int idx = t; idx < 32 * nq; idx += 256) {
      int r = idx / nq, q = idx - r * nq;
      int k = kt * 32 + r;
      unsigned short v0 = 0, v1 = 0, v2 = 0, v3 = 0;
      if (k < K) {
        const float4 f =
            *(const float4*)((const float*)src + ((long)(e * K + k) * N + q * 4));
        v0 = f2bf_rne(f.x); v1 = f2bf_rne(f.y);
        v2 = f2bf_rne(f.z); v3 = f2bf_rne(f.w);
      }
      unsigned* p = (unsigned*)(lds + r * NP + q * 4);  // 4B-aligned (NP even)
      p[0] = (unsigned)v0 | ((unsigned)v1 << 16);
      p[1] = (unsigned)v2 | ((unsigned)v3 << 16);
    }
  } else if (isbf && N == Npad) {
    // bf16, full-width rows: uint4 loads, 8 shorts/lane/iter
    const int no = Npad >> 3;
    for (int idx = t; idx < 32 * no; idx += 256) {
      int r = idx / no, q = idx - r * no;
      int k = kt * 32 + r;
      uint4 f = make_uint4(0u, 0u, 0u, 0u);
      if (k < K)
        f = *(const uint4*)((const unsigned short*)src + ((long)(e * K + k) * N + q * 8));
      unsigned* p = (unsigned*)(lds + r * NP + q * 8);  // 4B-aligned
      p[0] = f.x; p[1] = f.y; p[2] = f.z; p[3] = f.w;
    }
  } else {
    // scalar fallback (W4: N=33 ragged rows)
    for (int idx = t; idx < 32 * Npad; idx += 256) {
      int r = idx / Npad, c = idx - r * Npad;
      int k = kt * 32 + r;
      unsigned short v = 0;
      if (k < K && c < N) v = load_bf(src, (long)(e * K + k) * N + c, isbf);
      lds[r * NP + c] = v;
    }
  }
  __syncthreads();
  for (int u = t; u < NT * 64; u += 256) {
    int nt = u >> 6, kb = (u >> 4) & 3, ni = u & 15;
    int n = nt * 16 + ni;
    unsigned v[4];
#pragma unroll
    for (int p = 0; p < 4; ++p) {
      unsigned lo = lds[(kb * 8 + 2 * p) * NP + n];
      unsigned hi = lds[(kb * 8 + 2 * p + 1) * NP + n];
      v[p] = lo | (hi << 16);
    }
    long off = (long)e * perE + ((long)((kt * NT + nt) * 64 + kb * 16 + ni)) * 8;
    *(uint4*)(dst + off) = make_uint4(v[0], v[1], v[2], v[3]);
  }
}

__global__ void k_pack(const void* __restrict__ state, const void* __restrict__ action,
                       const void* __restrict__ W1, const void* __restrict__ W2,
                       const void* __restrict__ W3, const void* __restrict__ W4,
                       const void* __restrict__ b1, const void* __restrict__ b2,
                       const void* __restrict__ b3, const void* __restrict__ b4,
                       int isbfi,
                       unsigned short* __restrict__ saP, unsigned short* __restrict__ w1P,
                       unsigned short* __restrict__ w2P, unsigned short* __restrict__ w3P,
                       unsigned short* __restrict__ w4P, float* __restrict__ biasP) {
  __shared__ unsigned short lds[32 * 266];  // 17,024 B
  const bool isbf = (isbfi != 0);
  const int b = blockIdx.x;
  if (b < 400) {
    pack_w_panel(W2, w2P, isbf, b >> 3, b & 7, 256, 256, 16, 65536, lds);
  } else if (b < 800) {
    int bb = b - 400;
    pack_w_panel(W3, w3P, isbf, bb >> 3, bb & 7, 256, 256, 16, 65536, lds);
  } else if (b < 900) {
    int bb = b - 800;
    pack_w_panel(W1, w1P, isbf, bb >> 1, bb & 1, 40, 256, 16, 16384, lds);
  } else if (b < 1300) {
    int bb = b - 900;
    pack_w_panel(W4, w4P, isbf, bb >> 3, bb & 7, 256, 33, 3, 12288, lds);
  } else if (b < 1556) {
    // sa pack (B-frag units): addr(batch=mt*16+mi, k=kb*8+j) =
    //   (mt*128 + kb*16 + mi)*8 + j   (K padded 40->64)
    int u = (b - 1300) * 256 + threadIdx.x;  // < 65536
    int mi = u & 15, kb = (u >> 4) & 7, mt = u >> 7;
    int row = mt * 16 + mi;
    unsigned v[4] = {0u, 0u, 0u, 0u};
    if (kb < 4) {
#pragma unroll
      for (int p = 0; p < 4; ++p) {
        unsigned lo = load_bf(state, (long)row * 32 + kb * 8 + 2 * p, isbf);
        unsigned hi = load_bf(state, (long)row * 32 + kb * 8 + 2 * p + 1, isbf);
        v[p] = lo | (hi << 16);
      }
    } else if (kb == 4) {
#pragma unroll
      for (int p = 0; p < 4; ++p) {
        unsigned lo = load_bf(action, (long)row * 8 + 2 * p, isbf);
        unsigned hi = load_bf(action, (long)row * 8 + 2 * p + 1, isbf);
        v[p] = lo | (hi << 16);
      }
    }
    *(uint4*)(saP + (long)u * 8) = make_uint4(v[0], v[1], v[2], v[3]);
  } else {
    // bias: per e: [b1(256)][b2(256)][b3(256)][b4(48 zero-padded)]
    int gid = (b - 1556) * 256 + threadIdx.x;
    if (gid < NE * 816) {
      int e = gid / 816, r = gid - e * 816;
      float v = 0.0f;
      if (r < 256)      v = load_f(b1, e * 256 + r,         isbf);
      else if (r < 512) v = load_f(b2, e * 256 + (r - 256), isbf);
      else if (r < 768) v = load_f(b3, e * 256 + (r - 512), isbf);
      else { int q = r - 768; if (q < 33) v = load_f(b4, e * 33 + q, isbf); }
      biasP[gid] = v;
    }
  }
}

// ---------------- fused MLP ----------------
// hT in LDS (32KB), B-frag units for BM=64:
//   short addr(k,b) = ((k>>5)*4 + (b>>4))*512 + ((k>>3)&3)*128 + (b&15)*8 + (k&7)
// B-frag read (kt, bt): 16B at ((kt*4 + bt)*64 + l)*8.

__device__ __forceinline__ void store_tile16(const floatx4& a4, unsigned short* hT,
                                             int FT, int BT, int li, int g) {
  int k0 = FT * 16 + g * 4;
  unsigned d0 = pack_bf2(fmaxf(a4[0], 0.0f), fmaxf(a4[1], 0.0f));
  unsigned d1 = pack_bf2(fmaxf(a4[2], 0.0f), fmaxf(a4[3], 0.0f));
  int addr = ((k0 >> 5) * 4 + BT) * 512 + ((k0 >> 3) & 3) * 128 + li * 8 + (k0 & 7);
  *(unsigned long long*)(hT + addr) =
      (unsigned long long)d0 | ((unsigned long long)d1 << 32);
}

// wave wf owns feats [wf*64, wf*64+64) x all 64 batch: acc[4 ftiles][4 btiles]
__device__ __forceinline__ void hidden_layer(const unsigned short* __restrict__ wp,
                                             const float* __restrict__ br,
                                             unsigned short* hT,
                                             int wf, int l, int li, int g) {
  floatx4 acc[4][4];
#pragma unroll
  for (int ot = 0; ot < 4; ++ot) {
    const float4 bq = *(const float4*)(br + wf * 64 + ot * 16 + g * 4);
    floatx4 iv = {bq.x, bq.y, bq.z, bq.w};
#pragma unroll
    for (int bt = 0; bt < 4; ++bt) acc[ot][bt] = iv;
  }
#pragma unroll
  for (int kt = 0; kt < 8; ++kt) {
    short8 a[4];
#pragma unroll
    for (int ot = 0; ot < 4; ++ot)
      a[ot] = *(const short8*)(wp + (long)((kt * 16 + wf * 4 + ot) * 64 + l) * 8);
#pragma unroll
    for (int bt = 0; bt < 4; ++bt) {
      short8 b = *(const short8*)(hT + ((kt * 4 + bt) * 64 + l) * 8);
#pragma unroll
      for (int ot = 0; ot < 4; ++ot)
        acc[ot][bt] = mfma16(a[ot], b, acc[ot][bt]);
    }
  }
  __syncthreads();  // all reads of hT done before in-place overwrite
#pragma unroll
  for (int ot = 0; ot < 4; ++ot)
#pragma unroll
    for (int bt = 0; bt < 4; ++bt)
      store_tile16(acc[ot][bt], hT, wf * 4 + ot, bt, li, g);
  __syncthreads();
}

__global__ __launch_bounds__(256, 4) void k_mlp(
    const unsigned short* __restrict__ sa,
    const unsigned short* __restrict__ w1,
    const unsigned short* __restrict__ w2,
    const unsigned short* __restrict__ w3,
    const unsigned short* __restrict__ w4,
    const float* __restrict__ bias,
    int isbfi,
    float* __restrict__ rewardWS,
    void* __restrict__ outp) {
  __shared__ __attribute__((aligned(16))) unsigned short hT[16384];  // 32 KB
  const int tid = threadIdx.x;
  const int wf = tid >> 6, l = tid & 63, li = l & 15, g = l >> 4;

  // XCD-aware swizzle: hw assigns linear id round-robin (xcd = lid % 8).
  // swz = (lid%8)*800 + lid/8 gives each XCD a contiguous block range =>
  // contiguous ~6.25-ensemble window whose packed panels fit its 4MB L2.
  // 6400 % 8 == 0 -> bijective. (R8: FETCH 66->15.9MB, confirmed.)
  const int lid = blockIdx.y * 128 + blockIdx.x;
  const int swz = (lid & 7) * 800 + (lid >> 3);
  const int e  = swz >> 7;         // ensemble
  const int bb = swz & 127;        // 64-row batch tile (128 tiles)

  const float* brow = bias + e * 816;
  const bool isbf = (isbfi != 0);

  // ---- layer 1: W1^T(256x64) * sa^T(64x64) -> h1^T in LDS ----
  {
    floatx4 acc[4][4];
#pragma unroll
    for (int ot = 0; ot < 4; ++ot) {
      const float4 bq = *(const float4*)(brow + wf * 64 + ot * 16 + g * 4);
      floatx4 iv = {bq.x, bq.y, bq.z, bq.w};
#pragma unroll
      for (int bt = 0; bt < 4; ++bt) acc[ot][bt] = iv;
    }
#pragma unroll
    for (int kt = 0; kt < 2; ++kt) {
      short8 a[4];
#pragma unroll
      for (int ot = 0; ot < 4; ++ot)
        a[ot] = *(const short8*)(w1 + (long)e * 16384 +
                                 (long)((kt * 16 + wf * 4 + ot) * 64 + l) * 8);
#pragma unroll
      for (int bt = 0; bt < 4; ++bt) {
        short8 b = *(const short8*)(sa + (long)((bb * 4 + bt) * 128 + kt * 64 + l) * 8);
#pragma unroll
        for (int ot = 0; ot < 4; ++ot)
          acc[ot][bt] = mfma16(a[ot], b, acc[ot][bt]);
      }
    }
#pragma unroll
    for (int ot = 0; ot < 4; ++ot)
#pragma unroll
      for (int bt = 0; bt < 4; ++bt)
        store_tile16(acc[ot][bt], hT, wf * 4 + ot, bt, li, g);
    __syncthreads();
  }

  // ---- layers 2, 3 ----
  hidden_layer(w2 + (long)e * 65536, brow + 256, hT, wf, l, li, g);
  hidden_layer(w3 + (long)e * 65536, brow + 512, hT, wf, l, li, g);

  // ---- layer 4: W4^T(48x256) * h3^T(256x64); wave wf owns btile wf ----
  const float* brow4 = brow + 768;
  floatx4 acc4[3];
#pragma unroll
  for (int ft = 0; ft < 3; ++ft) {
    const float4 bq = *(const float4*)(brow4 + ft * 16 + g * 4);
    floatx4 iv = {bq.x, bq.y, bq.z, bq.w};
    acc4[ft] = iv;
  }
#pragma unroll
  for (int kt = 0; kt < 8; ++kt) {
    short8 a[3];
#pragma unroll
    for (int ft = 0; ft < 3; ++ft)
      a[ft] = *(const short8*)(w4 + (long)e * 12288 + (long)((kt * 3 + ft) * 64 + l) * 8);
    short8 b = *(const short8*)(hT + ((kt * 4 + wf) * 64 + l) * 8);
#pragma unroll
    for (int ft = 0; ft < 3; ++ft)
      acc4[ft] = mfma16(a[ft], b, acc4[ft]);
  }

  // reward (feat 32 = ft2, g==0, reg 0) -> staged coalesced into ws[e][batch]
  if (g == 0) {
    rewardWS[(long)e * NB + bb * 64 + wf * 16 + li] = acc4[2][0];
  }

  __syncthreads();  // all hT reads done; reuse hT as output staging buffer
  // stage out^T tiles -> osta[batch][feat] (bf16, stride OSTRIDE)
#pragma unroll
  for (int ft = 0; ft < 2; ++ft) {
    int batch = wf * 16 + li;
    unsigned d0 = pack_bf2(acc4[ft][0], acc4[ft][1]);
    unsigned d1 = pack_bf2(acc4[ft][2], acc4[ft][3]);
    *(unsigned long long*)(hT + batch * OSTRIDE + ft * 16 + g * 4) =
        (unsigned long long)d0 | ((unsigned long long)d1 << 32);
  }
  __syncthreads();

  // coalesced store: full 64B line per (batch,e)
  if (isbf) {
    unsigned short* o16 = (unsigned short*)outp;
    int batch = tid >> 2;
    int chunk = tid & 3;  // 8 shorts each
    uint4 v = *(const uint4*)(hT + batch * OSTRIDE + chunk * 8);
    *(uint4*)(o16 + ((long)(bb * 64 + batch) * NE + e) * 32 + chunk * 8) = v;
  } else {
    float* o32 = (float*)outp;
#pragma unroll
    for (int p = 0; p < 2; ++p) {
      int idx = p * 256 + tid;
      int batch = idx >> 3;
      int chunk = idx & 7;  // 4 floats each
      const unsigned short* s = hT + batch * OSTRIDE + chunk * 4;
      *(float4*)(o32 + ((long)(bb * 64 + batch) * NE + e) * 32 + chunk * 4) =
          make_float4(bf2f(s[0]), bf2f(s[1]), bf2f(s[2]), bf2f(s[3]));
    }
  }
}

// ---------------- reward transpose epilogue ----------------
__global__ void k_reward(const float* __restrict__ rw, int isbfi,
                         void* __restrict__ outp) {
  int id = blockIdx.x * 256 + threadIdx.x;
  if (id >= NB * NE) return;
  int b = id / NE, e = id - b * NE;
  float v = rw[(long)e * NB + b];
  if (isbfi != 0) {
    unsigned u = __float_as_uint(v) + 0x8000u;
    ((unsigned short*)outp)[OUT_NS_ELEMS + id] = (unsigned short)(u >> 16);
  } else {
    ((float*)outp)[OUT_NS_ELEMS + id] = v;
  }
}

// ---------------------------------------------------------------------------
extern "C" void kernel_launch(void* const* d_in, const int* in_sizes, int n_in,
                              void* d_out, int out_size, void* d_ws, size_t ws_size,
                              hipStream_t stream) {
  const void* state  = d_in[0];
  const void* action = d_in[1];
  const void* W1 = d_in[2];
  const void* b1 = d_in[3];
  const void* W2 = d_in[4];
  const void* b2 = d_in[5];
  const void* W3 = d_in[6];
  const void* b3 = d_in[7];
  const void* W4 = d_in[8];
  const void* b4 = d_in[9];
  (void)n_in; (void)out_size; (void)ws_size;

  // dtype from buffer size: W2 = 50*256*256 elems; bf16 -> 6,553,600 B.
  const int isbf = (in_sizes[4] == NE * 256 * 256 * 2) ? 1 : 0;

  char* ws = (char*)d_ws;
  unsigned short* saP    = (unsigned short*)(ws + 256);        // 1,048,576 B
  unsigned short* w1P    = (unsigned short*)(ws + 1048832);    // 1,638,400 B
  unsigned short* w2P    = (unsigned short*)(ws + 2687232);    // 6,553,600 B
  unsigned short* w3P    = (unsigned short*)(ws + 9240832);    // 6,553,600 B
  unsigned short* w4P    = (unsigned short*)(ws + 15794432);   // 1,228,800 B
  float* biasP           = (float*)(ws + 17023232);            //   163,200 B
  float* rewardWS        = (float*)(ws + 17186432);            // 1,638,400 B
  // total ws use: 18,824,832 B

  k_pack<<<1716, 256, 0, stream>>>(state, action, W1, W2, W3, W4, b1, b2, b3, b4,
                                   isbf, saP, w1P, w2P, w3P, w4P, biasP);
  k_mlp<<<dim3(128, 50), 256, 0, stream>>>(saP, w1P, w2P, w3P, w4P, biasP, isbf,
                                           rewardWS, d_out);
  k_reward<<<(NB * NE + 255) / 256, 256, 0, stream>>>(rewardWS, isbf, d_out);
}